// Round 4
// baseline (652.480 us; speedup 1.0000x reference)
//
#include <hip/hip_runtime.h>
#include <hip/hip_bf16.h>

// B=16, N=4096, C=256, WS=8 -> 1024 windows x 64 tokens; NH=8, HD=32, LK=32, G=16.
// R8: 3 blocks/CU. LDS 48KB: x staged in two 16KB halves (tk 0-3 / 4-7);
//   k/v/q GEMMs merged into one tk loop sharing xf frags, accumulating across
//   halves. P frag-bounce per-mt in 2KB/wave with XOR chunk swizzle
//   (chunk ^= (chunk>>3)&7) -> conflict-free scatter. 5 barriers.
//   (R7: wave-per-head, register dataflow, xpose via shfl.)

typedef unsigned int uint;
typedef __attribute__((ext_vector_type(8))) short short8;   // 8 x bf16
typedef __attribute__((ext_vector_type(4))) float f32x4;
typedef __attribute__((ext_vector_type(4))) uint uintx4;

__device__ __forceinline__ float bup(uint hs) {
    return __uint_as_float(hs << 16);
}
__device__ __forceinline__ uint f2b(float f) {   // fp32 -> bf16 bits (RNE, HW cvt)
    __hip_bfloat16 h = __float2bfloat16(f);
    unsigned short u;
    __builtin_memcpy(&u, &h, 2);
    return (uint)u;
}
__device__ __forceinline__ uint f2b2(float a, float b) {  // v_cvt_pk_bf16_f32
    __hip_bfloat162 h = __float22bfloat162_rn(make_float2(a, b));
    uint u;
    __builtin_memcpy(&u, &h, 4);
    return u;
}
__device__ __forceinline__ f32x4 mfma16(short8 a, short8 b, f32x4 c) {
    return __builtin_amdgcn_mfma_f32_16x16x32_bf16(a, b, c, 0, 0, 0);
}
__device__ __forceinline__ int sw256(int r, int c) { return r * 256 + (c ^ ((r & 7) << 3)); }
__device__ __forceinline__ int sw128(int r, int c) { return r * 128 + (c ^ ((r & 7) << 3)); }

// C-layout pair (a = rows 0-15, b = rows 16-31; lane = col l16, per-reg rows
// quad*4+r) -> MFMA operand frag: lane (qf,l16) elem j = (row qf*8+j, col l16).
__device__ __forceinline__ short8 xpose(f32x4 a, f32x4 b, float s, int lane) {
    const uint pa0 = f2b2(a[0] * s, a[1] * s), pa1 = f2b2(a[2] * s, a[3] * s);
    const uint pb0 = f2b2(b[0] * s, b[1] * s), pb1 = f2b2(b[2] * s, b[3] * s);
    const int s0 = ((lane >> 4) & 1) * 32 + (lane & 15);
    const int s1 = s0 + 16;
    const uint w0a = __shfl(pa0, s0), w0b = __shfl(pb0, s0);
    const uint w1a = __shfl(pa1, s0), w1b = __shfl(pb1, s0);
    const uint w2a = __shfl(pa0, s1), w2b = __shfl(pb0, s1);
    const uint w3a = __shfl(pa1, s1), w3b = __shfl(pb1, s1);
    const bool hi = lane >= 32;
    uintx4 u;
    u[0] = hi ? w0b : w0a;
    u[1] = hi ? w1b : w1a;
    u[2] = hi ? w2b : w2a;
    u[3] = hi ? w3b : w3a;
    short8 r;
    __builtin_memcpy(&r, &u, 16);
    return r;
}

// ---- workspace layout (shorts) ----
#define WS_WHQ 0          // Wqkv frags [48 tn][8 tk][64 lane][8] = 196608
#define WS_WHP 196608     // Wproj hi [16 tn][8 tk][64][8] = 65536
#define WS_WLP 262144     // Wproj lo = 65536
#define WS_EKT 327680     // Ek frags [2 tm][2 tk][64][8] = 2048
#define WS_EVT 329728     // Ev frags = 2048
#define WS_KBF 331776     // kbank frags [8 h][64][8] = 4096
#define WS_VBF 335872     // vbank frags [8 h][2 md][64][8] = 8192 (quads>=2 zero)

__global__ void __launch_bounds__(256)
eswa_prep(const float* __restrict__ Wqkv, const float* __restrict__ Wproj,
          const float* __restrict__ Ek, const float* __restrict__ Ev,
          const float* __restrict__ kbank, const float* __restrict__ vbank,
          short* __restrict__ wsp)
{
    const int blk = blockIdx.x, thr = threadIdx.x;
    if (blk < 192) {                      // Wqkv frags
        const int jh = blk & 1;
        const int g = (blk >> 1) * 256 + thr;
        const int lane = g & 63, tk = (g >> 6) & 7, tn = g >> 9;
        const int quad = lane >> 4, l16 = lane & 15;
        const int c = tn * 16 + l16;
        const int r0 = tk * 32 + quad * 8 + jh * 4;
        const float w0 = Wqkv[(r0 + 0) * 768 + c], w1 = Wqkv[(r0 + 1) * 768 + c];
        const float w2 = Wqkv[(r0 + 2) * 768 + c], w3 = Wqkv[(r0 + 3) * 768 + c];
        *(uint2*)(wsp + WS_WHQ + ((tn * 8 + tk) * 64 + lane) * 8 + jh * 4) =
            make_uint2(f2b2(w0, w1), f2b2(w2, w3));
    } else if (blk < 256) {               // Wproj hi+lo
        const int idx = blk - 192, jh = idx & 1;
        const int g = (idx >> 1) * 256 + thr;
        const int lane = g & 63, tk = (g >> 6) & 7, tn = g >> 9;
        const int quad = lane >> 4, l16 = lane & 15;
        const int c = tn * 16 + l16;
        const int r0 = tk * 32 + quad * 8 + jh * 4;
        float w[4];
        #pragma unroll
        for (int j = 0; j < 4; ++j) w[j] = Wproj[(r0 + j) * 256 + c];
        const uint h01 = f2b2(w[0], w[1]), h23 = f2b2(w[2], w[3]);
        const float l0 = w[0] - bup(h01 & 0xffffu), l1 = w[1] - bup(h01 >> 16);
        const float l2 = w[2] - bup(h23 & 0xffffu), l3 = w[3] - bup(h23 >> 16);
        const int o = ((tn * 8 + tk) * 64 + lane) * 8 + jh * 4;
        *(uint2*)(wsp + WS_WHP + o) = make_uint2(h01, h23);
        *(uint2*)(wsp + WS_WLP + o) = make_uint2(f2b2(l0, l1), f2b2(l2, l3));
    } else if (blk < 258) {               // Ek (256) / Ev (257) frags
        const float* E = (blk == 256) ? Ek : Ev;
        const int base = (blk == 256) ? WS_EKT : WS_EVT;
        const int lane = thr & 63, tk = (thr >> 6) & 1, tm = (thr >> 7) & 1;
        const int quad = lane >> 4, l16 = lane & 15;
        const int lk = tm * 16 + l16;
        uint pk[4];
        #pragma unroll
        for (int jp = 0; jp < 4; ++jp) {
            const int t = tk * 32 + quad * 8 + jp * 2;
            pk[jp] = f2b2(E[t * 32 + lk], E[(t + 1) * 32 + lk]);
        }
        *(uint4*)(wsp + base + ((tm * 2 + tk) * 64 + lane) * 8) =
            make_uint4(pk[0], pk[1], pk[2], pk[3]);
    } else {                              // bank fragments
        for (int idx = thr; idx < 512; idx += 256) {
            const int hh = idx >> 6, l = idx & 63;
            const int l16 = l & 15, q = l >> 4;
            uint pk[4];
            #pragma unroll
            for (int jp = 0; jp < 4; ++jp)
                pk[jp] = f2b2(kbank[l16 * 256 + hh * 32 + q * 8 + jp * 2],
                              kbank[l16 * 256 + hh * 32 + q * 8 + jp * 2 + 1]);
            *(uint4*)(wsp + WS_KBF + idx * 8) = make_uint4(pk[0], pk[1], pk[2], pk[3]);
        }
        for (int idx = thr; idx < 1024; idx += 256) {
            const int hh = idx >> 7, md = (idx >> 6) & 1, l = idx & 63;
            const int l16 = l & 15, q = l >> 4;
            uint pk[4] = {0u, 0u, 0u, 0u};
            if (q < 2) {
                #pragma unroll
                for (int jp = 0; jp < 4; ++jp)
                    pk[jp] = f2b2(vbank[(q * 8 + jp * 2) * 256 + hh * 32 + md * 16 + l16],
                                  vbank[(q * 8 + jp * 2 + 1) * 256 + hh * 32 + md * 16 + l16]);
            }
            *(uint4*)(wsp + WS_VBF + idx * 8) = make_uint4(pk[0], pk[1], pk[2], pk[3]);
        }
    }
}

// ---- LDS (bytes), total 49152 (48KB -> 3 blocks/CU) ----
// xh   bf16 [64][128] sw128 @ 0     16384  (one tk-half of x; dead after the
//                                           QKV loop; per-wave 2KB P scratch
//                                           overlays it after B4)
// attn bf16 [64][256] sw256 @ 16384 32768
#define SMEM_BYTES 49152

__global__ void __launch_bounds__(512, 6)
eswa_main(const float* __restrict__ x, const float* __restrict__ bqkv,
          const float* __restrict__ bproj, const short* __restrict__ wsp,
          float* __restrict__ out)
{
    extern __shared__ char smem[];
    short* xh   = (short*)smem;            // [64][128] sw128
    short* attn = (short*)smem + 8192;     // [64][256] sw256

    const int tid  = threadIdx.x;
    const int wave = tid >> 6;             // 0..7 = head
    const int lane = tid & 63;
    const int quad = lane >> 4;
    const int l16  = lane & 15;
    const int h    = wave;

    const int b  = blockIdx.x >> 6;
    const int w  = blockIdx.x & 63;
    const int rw = w >> 3;
    const int cw = w & 7;

    const short* WF = wsp + WS_WHQ;

    // ============ phase 1: merged k/v/q GEMM over two x halves ============
    f32x4 kacc[2][4], vacc[2][4], qacc[2][4];
    #pragma unroll
    for (int nd = 0; nd < 2; ++nd) {
        const float bk = bqkv[256 + h * 32 + nd * 16 + l16];
        const float bv = bqkv[512 + h * 32 + nd * 16 + l16];
        #pragma unroll
        for (int mt = 0; mt < 4; ++mt) {
            kacc[nd][mt] = (f32x4){bk, bk, bk, bk};
            vacc[nd][mt] = (f32x4){bv, bv, bv, bv};
        }
    }
    #pragma unroll
    for (int md = 0; md < 2; ++md) {
        const float4 bq = *(const float4*)(bqkv + h * 32 + md * 16 + quad * 4);
        #pragma unroll
        for (int nt = 0; nt < 4; ++nt) qacc[md][nt] = (f32x4){bq.x, bq.y, bq.z, bq.w};
    }

    for (int hf = 0; hf < 2; ++hf) {
        if (hf) __syncthreads();          // prior half's readers done
        #pragma unroll
        for (int i = 0; i < 4; ++i) {
            const int vi = tid + 512 * i;         // 0..2047
            const int t  = vi >> 5;
            const int cl = (vi & 31) * 4;         // local col 0..124
            const int n  = (rw * 8 + (t >> 3)) * 64 + cw * 8 + (t & 7);
            const float4 xv =
                *(const float4*)(x + (size_t)(b * 4096 + n) * 256 + hf * 128 + cl);
            *(uint2*)(xh + sw128(t, cl)) = make_uint2(f2b2(xv.x, xv.y), f2b2(xv.z, xv.w));
        }
        __syncthreads();
        #pragma unroll
        for (int t4 = 0; t4 < 4; ++t4) {
            const int tk = hf * 4 + t4;
            short8 xf[4];
            #pragma unroll
            for (int mt = 0; mt < 4; ++mt)
                xf[mt] = *(const short8*)(xh + sw128(mt * 16 + l16, t4 * 32 + quad * 8));
            #pragma unroll
            for (int nd = 0; nd < 2; ++nd) {
                const short8 wk =
                    *(const short8*)(WF + (((16 + h * 2 + nd) * 8 + tk) * 64 + lane) * 8);
                #pragma unroll
                for (int mt = 0; mt < 4; ++mt) kacc[nd][mt] = mfma16(xf[mt], wk, kacc[nd][mt]);
            }
            #pragma unroll
            for (int nd = 0; nd < 2; ++nd) {
                const short8 wv =
                    *(const short8*)(WF + (((32 + h * 2 + nd) * 8 + tk) * 64 + lane) * 8);
                #pragma unroll
                for (int mt = 0; mt < 4; ++mt) vacc[nd][mt] = mfma16(xf[mt], wv, vacc[nd][mt]);
            }
            #pragma unroll
            for (int md = 0; md < 2; ++md) {
                const short8 wq =
                    *(const short8*)(WF + (((h * 2 + md) * 8 + tk) * 64 + lane) * 8);
                #pragma unroll
                for (int nt = 0; nt < 4; ++nt) qacc[md][nt] = mfma16(wq, xf[nt], qacc[md][nt]);
            }
        }
    }
    __syncthreads();   // B4: xh dead everywhere -> P scratch may overlay

    // ---- register transposes to operand fragments
    short8 kfr[2][2], vfr[2][2];
    #pragma unroll
    for (int nd = 0; nd < 2; ++nd)
        #pragma unroll
        for (int kk = 0; kk < 2; ++kk) {
            kfr[nd][kk] = xpose(kacc[nd][2 * kk], kacc[nd][2 * kk + 1], 1.0f, lane);
            vfr[nd][kk] = xpose(vacc[nd][2 * kk], vacc[nd][2 * kk + 1], 1.0f, lane);
        }
    short8 qfr[4];
    #pragma unroll
    for (int nt = 0; nt < 4; ++nt)
        qfr[nt] = xpose(qacc[0][nt], qacc[1][nt], 0.17677669529663687f, lane);

    // ---- Linformer compression, in registers
    short8 kcf[2], vcf[2];
    {
        short8 ekf[2][2], evf[2][2];
        #pragma unroll
        for (int tm = 0; tm < 2; ++tm)
            #pragma unroll
            for (int kk = 0; kk < 2; ++kk) {
                ekf[tm][kk] = *(const short8*)(wsp + WS_EKT + ((tm * 2 + kk) * 64 + lane) * 8);
                evf[tm][kk] = *(const short8*)(wsp + WS_EVT + ((tm * 2 + kk) * 64 + lane) * 8);
            }
        f32x4 ck[2][2];
        #pragma unroll
        for (int md = 0; md < 2; ++md)
            #pragma unroll
            for (int nl = 0; nl < 2; ++nl) ck[md][nl] = (f32x4){0, 0, 0, 0};
        #pragma unroll
        for (int kk = 0; kk < 2; ++kk)
            #pragma unroll
            for (int md = 0; md < 2; ++md)
                #pragma unroll
                for (int nl = 0; nl < 2; ++nl)
                    ck[md][nl] = mfma16(kfr[md][kk], ekf[nl][kk], ck[md][nl]);
        #pragma unroll
        for (int nl = 0; nl < 2; ++nl)
            kcf[nl] = xpose(ck[0][nl], ck[1][nl], 1.0f, lane);
        f32x4 cv[2][2];
        #pragma unroll
        for (int ml = 0; ml < 2; ++ml)
            #pragma unroll
            for (int nd = 0; nd < 2; ++nd) cv[ml][nd] = (f32x4){0, 0, 0, 0};
        #pragma unroll
        for (int kk = 0; kk < 2; ++kk)
            #pragma unroll
            for (int ml = 0; ml < 2; ++ml)
                #pragma unroll
                for (int nd = 0; nd < 2; ++nd)
                    cv[ml][nd] = mfma16(evf[ml][kk], vfr[nd][kk], cv[ml][nd]);
        #pragma unroll
        for (int nd = 0; nd < 2; ++nd)
            vcf[nd] = xpose(cv[0][nd], cv[1][nd], 1.0f, lane);
    }
    const short8 kbf = *(const short8*)(wsp + WS_KBF + (h * 64 + lane) * 8);
    short8 vbf[2];
    #pragma unroll
    for (int md = 0; md < 2; ++md)
        vbf[md] = *(const short8*)(wsp + WS_VBF + ((h * 2 + md) * 64 + lane) * 8);

    // ============ phase 2: scores/softmax/PV (wave-local) ============
    short* scr = (short*)smem + wave * 1024;   // 2KB/wave, 128 16B chunks
    // zero pad chunks (kk=1, lanes>=32), swizzled; never overwritten
    if (lane >= 32) {
        const int ch = (64 + lane) ^ ((lane >> 3) & 7);
        *(uint4*)(scr + ch * 8) = make_uint4(0, 0, 0, 0);
    }
    const int rdx0 = (lane ^ ((lane >> 3) & 7)) * 8;
    const int rdx1 = ((64 + lane) ^ ((lane >> 3) & 7)) * 8;

    #pragma unroll
    for (int th = 0; th < 2; ++th) {
        f32x4 sc[2][3];
        #pragma unroll
        for (int mt = 0; mt < 2; ++mt) {
            const short8 qa = qfr[th * 2 + mt];
            sc[mt][0] = mfma16(qa, kcf[0], (f32x4){0, 0, 0, 0});
            sc[mt][1] = mfma16(qa, kcf[1], (f32x4){0, 0, 0, 0});
            sc[mt][2] = mfma16(qa, kbf,    (f32x4){0, 0, 0, 0});
        }
        float inv[2][4];
        #pragma unroll
        for (int mt = 0; mt < 2; ++mt) {
            #pragma unroll
            for (int r = 0; r < 4; ++r) {
                float mm = fmaxf(fmaxf(sc[mt][0][r], sc[mt][1][r]), sc[mt][2][r]);
                mm = fmaxf(mm, __shfl_xor(mm, 1));
                mm = fmaxf(mm, __shfl_xor(mm, 2));
                mm = fmaxf(mm, __shfl_xor(mm, 4));
                mm = fmaxf(mm, __shfl_xor(mm, 8));
                const float e0 = __expf(sc[mt][0][r] - mm);
                const float e1 = __expf(sc[mt][1][r] - mm);
                const float e2 = __expf(sc[mt][2][r] - mm);
                sc[mt][0][r] = e0; sc[mt][1][r] = e1; sc[mt][2][r] = e2;
                float su = e0 + e1 + e2;
                su += __shfl_xor(su, 1);
                su += __shfl_xor(su, 2);
                su += __shfl_xor(su, 4);
                su += __shfl_xor(su, 8);
                inv[mt][r] = 1.0f / su;
            }
        }
        #pragma unroll
        for (int mt = 0; mt < 2; ++mt) {
            // scatter P (this mt) into swizzled frag chunks
            #pragma unroll
            for (int nk = 0; nk < 3; ++nk) {
                const int qt = (nk * 2 + (l16 >> 3)) & 3;
                const int kk = nk >> 1;
                const int xr = (qt * 2 + (quad >> 1)) & 7;
                #pragma unroll
                for (int r = 0; r < 4; ++r) {
                    const int ch = (kk * 64 + qt * 16 + quad * 4 + r) ^ xr;
                    scr[ch * 8 + (l16 & 7)] = (short)f2b(sc[mt][nk][r] * inv[mt][r]);
                }
            }
            asm volatile("s_waitcnt lgkmcnt(0)" ::: "memory");
            __builtin_amdgcn_sched_barrier(0);
            const short8 pa0 = *(const short8*)(scr + rdx0);
            const short8 pa1 = *(const short8*)(scr + rdx1);
            #pragma unroll
            for (int md = 0; md < 2; ++md) {
                f32x4 o = mfma16(vcf[md], pa0, (f32x4){0, 0, 0, 0});
                o = mfma16(vbf[md], pa1, o);
                *(uint2*)(attn + sw256((th * 2 + mt) * 16 + l16,
                                       h * 32 + md * 16 + quad * 4)) =
                    make_uint2(f2b2(o[0], o[1]), f2b2(o[2], o[3]));
            }
        }
    }
    __syncthreads();   // B5: attn ready

    // ============ phase 3: output projection ============
    {
        const short* Whp = wsp + WS_WHP;
        const short* Wlp = wsp + WS_WLP;
        f32x4 acc[2][4];
        #pragma unroll
        for (int p = 0; p < 2; ++p) {
            const float bi = bproj[(wave * 2 + p) * 16 + l16];
            #pragma unroll
            for (int m = 0; m < 4; ++m) acc[p][m] = (f32x4){bi, bi, bi, bi};
        }
        #pragma unroll 2
        for (int tk = 0; tk < 8; ++tk) {
            short8 aA[4];
            #pragma unroll
            for (int m = 0; m < 4; ++m)
                aA[m] = *(const short8*)(attn + sw256(m * 16 + l16, tk * 32 + quad * 8));
            #pragma unroll
            for (int p = 0; p < 2; ++p) {
                const int bo = (((wave * 2 + p) * 8 + tk) * 64 + lane) * 8;
                const short8 bh = *(const short8*)(Whp + bo);
                const short8 bl = *(const short8*)(Wlp + bo);
                #pragma unroll
                for (int m = 0; m < 4; ++m) {
                    acc[p][m] = mfma16(aA[m], bh, acc[p][m]);
                    acc[p][m] = mfma16(aA[m], bl, acc[p][m]);
                }
            }
        }
        #pragma unroll
        for (int p = 0; p < 2; ++p)
            #pragma unroll
            for (int m = 0; m < 4; ++m)
                #pragma unroll
                for (int r = 0; r < 4; ++r) {
                    const int t = m * 16 + quad * 4 + r;
                    const int n = (rw * 8 + (t >> 3)) * 64 + cw * 8 + (t & 7);
                    out[(size_t)(b * 4096 + n) * 256 + (wave * 2 + p) * 16 + l16] =
                        acc[p][m][r];
                }
    }
}

extern "C" void kernel_launch(void* const* d_in, const int* in_sizes, int n_in,
                              void* d_out, int out_size, void* d_ws, size_t ws_size,
                              hipStream_t stream) {
    const float* x     = (const float*)d_in[0];
    const float* Wqkv  = (const float*)d_in[1];
    const float* bqkv  = (const float*)d_in[2];
    const float* Ek    = (const float*)d_in[3];
    const float* Ev    = (const float*)d_in[4];
    const float* kbank = (const float*)d_in[5];
    const float* vbank = (const float*)d_in[6];
    const float* Wproj = (const float*)d_in[7];
    const float* bproj = (const float*)d_in[8];
    float* outp        = (float*)d_out;
    short* wsp         = (short*)d_ws;
    (void)in_sizes; (void)n_in; (void)out_size; (void)ws_size;

    (void)hipFuncSetAttribute((const void*)eswa_main,
                              hipFuncAttributeMaxDynamicSharedMemorySize, SMEM_BYTES);

    eswa_prep<<<259, 256, 0, stream>>>(Wqkv, Wproj, Ek, Ev, kbank, vbank, wsp);
    eswa_main<<<1024, 512, SMEM_BYTES, stream>>>(x, bqkv, bproj, wsp, outp);
}

// Round 5
// 227.429 us; speedup vs baseline: 2.8689x; 2.8689x over previous
//
#include <hip/hip_runtime.h>
#include <hip/hip_bf16.h>

// B=16, N=4096, C=256, WS=8 -> 1024 windows x 64 tokens; NH=8, HD=32, LK=32, G=16.
// R9: R8 structure with __launch_bounds__(512) (no min-waves). R8's (512,6)
//   imposed a 256/6=40 VGPR compiler cap -> wholesale scratch spill (2GB HBM
//   traffic, 560us). Empirical rule: VGPR cap = 256/min_waves_per_EU. With no
//   cap the register-resident dataflow fits (~150 VGPR), occupancy stays
//   LDS-limited at 3 blocks/CU (48KB x 3 = 144KB).
// R8: 3 blocks/CU, x staged in two 16KB halves, merged k/v/q GEMM loop,
//   P frag-bounce 2KB/wave XOR-swizzled. 5 barriers. R7: wave-per-head,
//   register dataflow, xpose via shfl.

typedef unsigned int uint;
typedef __attribute__((ext_vector_type(8))) short short8;   // 8 x bf16
typedef __attribute__((ext_vector_type(4))) float f32x4;
typedef __attribute__((ext_vector_type(4))) uint uintx4;

__device__ __forceinline__ float bup(uint hs) {
    return __uint_as_float(hs << 16);
}
__device__ __forceinline__ uint f2b(float f) {   // fp32 -> bf16 bits (RNE, HW cvt)
    __hip_bfloat16 h = __float2bfloat16(f);
    unsigned short u;
    __builtin_memcpy(&u, &h, 2);
    return (uint)u;
}
__device__ __forceinline__ uint f2b2(float a, float b) {  // v_cvt_pk_bf16_f32
    __hip_bfloat162 h = __float22bfloat162_rn(make_float2(a, b));
    uint u;
    __builtin_memcpy(&u, &h, 4);
    return u;
}
__device__ __forceinline__ f32x4 mfma16(short8 a, short8 b, f32x4 c) {
    return __builtin_amdgcn_mfma_f32_16x16x32_bf16(a, b, c, 0, 0, 0);
}
__device__ __forceinline__ int sw256(int r, int c) { return r * 256 + (c ^ ((r & 7) << 3)); }
__device__ __forceinline__ int sw128(int r, int c) { return r * 128 + (c ^ ((r & 7) << 3)); }

// C-layout pair (a = rows 0-15, b = rows 16-31; lane = col l16, per-reg rows
// quad*4+r) -> MFMA operand frag: lane (qf,l16) elem j = (row qf*8+j, col l16).
__device__ __forceinline__ short8 xpose(f32x4 a, f32x4 b, float s, int lane) {
    const uint pa0 = f2b2(a[0] * s, a[1] * s), pa1 = f2b2(a[2] * s, a[3] * s);
    const uint pb0 = f2b2(b[0] * s, b[1] * s), pb1 = f2b2(b[2] * s, b[3] * s);
    const int s0 = ((lane >> 4) & 1) * 32 + (lane & 15);
    const int s1 = s0 + 16;
    const uint w0a = __shfl(pa0, s0), w0b = __shfl(pb0, s0);
    const uint w1a = __shfl(pa1, s0), w1b = __shfl(pb1, s0);
    const uint w2a = __shfl(pa0, s1), w2b = __shfl(pb0, s1);
    const uint w3a = __shfl(pa1, s1), w3b = __shfl(pb1, s1);
    const bool hi = lane >= 32;
    uintx4 u;
    u[0] = hi ? w0b : w0a;
    u[1] = hi ? w1b : w1a;
    u[2] = hi ? w2b : w2a;
    u[3] = hi ? w3b : w3a;
    short8 r;
    __builtin_memcpy(&r, &u, 16);
    return r;
}

// ---- workspace layout (shorts) ----
#define WS_WHQ 0          // Wqkv frags [48 tn][8 tk][64 lane][8] = 196608
#define WS_WHP 196608     // Wproj hi [16 tn][8 tk][64][8] = 65536
#define WS_WLP 262144     // Wproj lo = 65536
#define WS_EKT 327680     // Ek frags [2 tm][2 tk][64][8] = 2048
#define WS_EVT 329728     // Ev frags = 2048
#define WS_KBF 331776     // kbank frags [8 h][64][8] = 4096
#define WS_VBF 335872     // vbank frags [8 h][2 md][64][8] = 8192 (quads>=2 zero)

__global__ void __launch_bounds__(256)
eswa_prep(const float* __restrict__ Wqkv, const float* __restrict__ Wproj,
          const float* __restrict__ Ek, const float* __restrict__ Ev,
          const float* __restrict__ kbank, const float* __restrict__ vbank,
          short* __restrict__ wsp)
{
    const int blk = blockIdx.x, thr = threadIdx.x;
    if (blk < 192) {                      // Wqkv frags
        const int jh = blk & 1;
        const int g = (blk >> 1) * 256 + thr;
        const int lane = g & 63, tk = (g >> 6) & 7, tn = g >> 9;
        const int quad = lane >> 4, l16 = lane & 15;
        const int c = tn * 16 + l16;
        const int r0 = tk * 32 + quad * 8 + jh * 4;
        const float w0 = Wqkv[(r0 + 0) * 768 + c], w1 = Wqkv[(r0 + 1) * 768 + c];
        const float w2 = Wqkv[(r0 + 2) * 768 + c], w3 = Wqkv[(r0 + 3) * 768 + c];
        *(uint2*)(wsp + WS_WHQ + ((tn * 8 + tk) * 64 + lane) * 8 + jh * 4) =
            make_uint2(f2b2(w0, w1), f2b2(w2, w3));
    } else if (blk < 256) {               // Wproj hi+lo
        const int idx = blk - 192, jh = idx & 1;
        const int g = (idx >> 1) * 256 + thr;
        const int lane = g & 63, tk = (g >> 6) & 7, tn = g >> 9;
        const int quad = lane >> 4, l16 = lane & 15;
        const int c = tn * 16 + l16;
        const int r0 = tk * 32 + quad * 8 + jh * 4;
        float w[4];
        #pragma unroll
        for (int j = 0; j < 4; ++j) w[j] = Wproj[(r0 + j) * 256 + c];
        const uint h01 = f2b2(w[0], w[1]), h23 = f2b2(w[2], w[3]);
        const float l0 = w[0] - bup(h01 & 0xffffu), l1 = w[1] - bup(h01 >> 16);
        const float l2 = w[2] - bup(h23 & 0xffffu), l3 = w[3] - bup(h23 >> 16);
        const int o = ((tn * 8 + tk) * 64 + lane) * 8 + jh * 4;
        *(uint2*)(wsp + WS_WHP + o) = make_uint2(h01, h23);
        *(uint2*)(wsp + WS_WLP + o) = make_uint2(f2b2(l0, l1), f2b2(l2, l3));
    } else if (blk < 258) {               // Ek (256) / Ev (257) frags
        const float* E = (blk == 256) ? Ek : Ev;
        const int base = (blk == 256) ? WS_EKT : WS_EVT;
        const int lane = thr & 63, tk = (thr >> 6) & 1, tm = (thr >> 7) & 1;
        const int quad = lane >> 4, l16 = lane & 15;
        const int lk = tm * 16 + l16;
        uint pk[4];
        #pragma unroll
        for (int jp = 0; jp < 4; ++jp) {
            const int t = tk * 32 + quad * 8 + jp * 2;
            pk[jp] = f2b2(E[t * 32 + lk], E[(t + 1) * 32 + lk]);
        }
        *(uint4*)(wsp + base + ((tm * 2 + tk) * 64 + lane) * 8) =
            make_uint4(pk[0], pk[1], pk[2], pk[3]);
    } else {                              // bank fragments
        for (int idx = thr; idx < 512; idx += 256) {
            const int hh = idx >> 6, l = idx & 63;
            const int l16 = l & 15, q = l >> 4;
            uint pk[4];
            #pragma unroll
            for (int jp = 0; jp < 4; ++jp)
                pk[jp] = f2b2(kbank[l16 * 256 + hh * 32 + q * 8 + jp * 2],
                              kbank[l16 * 256 + hh * 32 + q * 8 + jp * 2 + 1]);
            *(uint4*)(wsp + WS_KBF + idx * 8) = make_uint4(pk[0], pk[1], pk[2], pk[3]);
        }
        for (int idx = thr; idx < 1024; idx += 256) {
            const int hh = idx >> 7, md = (idx >> 6) & 1, l = idx & 63;
            const int l16 = l & 15, q = l >> 4;
            uint pk[4] = {0u, 0u, 0u, 0u};
            if (q < 2) {
                #pragma unroll
                for (int jp = 0; jp < 4; ++jp)
                    pk[jp] = f2b2(vbank[(q * 8 + jp * 2) * 256 + hh * 32 + md * 16 + l16],
                                  vbank[(q * 8 + jp * 2 + 1) * 256 + hh * 32 + md * 16 + l16]);
            }
            *(uint4*)(wsp + WS_VBF + idx * 8) = make_uint4(pk[0], pk[1], pk[2], pk[3]);
        }
    }
}

// ---- LDS (bytes), total 49152 (48KB -> 3 blocks/CU) ----
// xh   bf16 [64][128] sw128 @ 0     16384  (one tk-half of x; dead after the
//                                           QKV loop; per-wave 2KB P scratch
//                                           overlays it after B4)
// attn bf16 [64][256] sw256 @ 16384 32768
#define SMEM_BYTES 49152

__global__ void __launch_bounds__(512)
eswa_main(const float* __restrict__ x, const float* __restrict__ bqkv,
          const float* __restrict__ bproj, const short* __restrict__ wsp,
          float* __restrict__ out)
{
    extern __shared__ char smem[];
    short* xh   = (short*)smem;            // [64][128] sw128
    short* attn = (short*)smem + 8192;     // [64][256] sw256

    const int tid  = threadIdx.x;
    const int wave = tid >> 6;             // 0..7 = head
    const int lane = tid & 63;
    const int quad = lane >> 4;
    const int l16  = lane & 15;
    const int h    = wave;

    const int b  = blockIdx.x >> 6;
    const int w  = blockIdx.x & 63;
    const int rw = w >> 3;
    const int cw = w & 7;

    const short* WF = wsp + WS_WHQ;

    // ============ phase 1: merged k/v/q GEMM over two x halves ============
    f32x4 kacc[2][4], vacc[2][4], qacc[2][4];
    #pragma unroll
    for (int nd = 0; nd < 2; ++nd) {
        const float bk = bqkv[256 + h * 32 + nd * 16 + l16];
        const float bv = bqkv[512 + h * 32 + nd * 16 + l16];
        #pragma unroll
        for (int mt = 0; mt < 4; ++mt) {
            kacc[nd][mt] = (f32x4){bk, bk, bk, bk};
            vacc[nd][mt] = (f32x4){bv, bv, bv, bv};
        }
    }
    #pragma unroll
    for (int md = 0; md < 2; ++md) {
        const float4 bq = *(const float4*)(bqkv + h * 32 + md * 16 + quad * 4);
        #pragma unroll
        for (int nt = 0; nt < 4; ++nt) qacc[md][nt] = (f32x4){bq.x, bq.y, bq.z, bq.w};
    }

    for (int hf = 0; hf < 2; ++hf) {
        if (hf) __syncthreads();          // prior half's readers done
        #pragma unroll
        for (int i = 0; i < 4; ++i) {
            const int vi = tid + 512 * i;         // 0..2047
            const int t  = vi >> 5;
            const int cl = (vi & 31) * 4;         // local col 0..124
            const int n  = (rw * 8 + (t >> 3)) * 64 + cw * 8 + (t & 7);
            const float4 xv =
                *(const float4*)(x + (size_t)(b * 4096 + n) * 256 + hf * 128 + cl);
            *(uint2*)(xh + sw128(t, cl)) = make_uint2(f2b2(xv.x, xv.y), f2b2(xv.z, xv.w));
        }
        __syncthreads();
        #pragma unroll
        for (int t4 = 0; t4 < 4; ++t4) {
            const int tk = hf * 4 + t4;
            short8 xf[4];
            #pragma unroll
            for (int mt = 0; mt < 4; ++mt)
                xf[mt] = *(const short8*)(xh + sw128(mt * 16 + l16, t4 * 32 + quad * 8));
            #pragma unroll
            for (int nd = 0; nd < 2; ++nd) {
                const short8 wk =
                    *(const short8*)(WF + (((16 + h * 2 + nd) * 8 + tk) * 64 + lane) * 8);
                #pragma unroll
                for (int mt = 0; mt < 4; ++mt) kacc[nd][mt] = mfma16(xf[mt], wk, kacc[nd][mt]);
            }
            #pragma unroll
            for (int nd = 0; nd < 2; ++nd) {
                const short8 wv =
                    *(const short8*)(WF + (((32 + h * 2 + nd) * 8 + tk) * 64 + lane) * 8);
                #pragma unroll
                for (int mt = 0; mt < 4; ++mt) vacc[nd][mt] = mfma16(xf[mt], wv, vacc[nd][mt]);
            }
            #pragma unroll
            for (int md = 0; md < 2; ++md) {
                const short8 wq =
                    *(const short8*)(WF + (((h * 2 + md) * 8 + tk) * 64 + lane) * 8);
                #pragma unroll
                for (int nt = 0; nt < 4; ++nt) qacc[md][nt] = mfma16(wq, xf[nt], qacc[md][nt]);
            }
        }
    }
    __syncthreads();   // B4: xh dead everywhere -> P scratch may overlay

    // ---- register transposes to operand fragments
    short8 kfr[2][2], vfr[2][2];
    #pragma unroll
    for (int nd = 0; nd < 2; ++nd)
        #pragma unroll
        for (int kk = 0; kk < 2; ++kk) {
            kfr[nd][kk] = xpose(kacc[nd][2 * kk], kacc[nd][2 * kk + 1], 1.0f, lane);
            vfr[nd][kk] = xpose(vacc[nd][2 * kk], vacc[nd][2 * kk + 1], 1.0f, lane);
        }
    short8 qfr[4];
    #pragma unroll
    for (int nt = 0; nt < 4; ++nt)
        qfr[nt] = xpose(qacc[0][nt], qacc[1][nt], 0.17677669529663687f, lane);

    // ---- Linformer compression, in registers
    short8 kcf[2], vcf[2];
    {
        short8 ekf[2][2], evf[2][2];
        #pragma unroll
        for (int tm = 0; tm < 2; ++tm)
            #pragma unroll
            for (int kk = 0; kk < 2; ++kk) {
                ekf[tm][kk] = *(const short8*)(wsp + WS_EKT + ((tm * 2 + kk) * 64 + lane) * 8);
                evf[tm][kk] = *(const short8*)(wsp + WS_EVT + ((tm * 2 + kk) * 64 + lane) * 8);
            }
        f32x4 ck[2][2];
        #pragma unroll
        for (int md = 0; md < 2; ++md)
            #pragma unroll
            for (int nl = 0; nl < 2; ++nl) ck[md][nl] = (f32x4){0, 0, 0, 0};
        #pragma unroll
        for (int kk = 0; kk < 2; ++kk)
            #pragma unroll
            for (int md = 0; md < 2; ++md)
                #pragma unroll
                for (int nl = 0; nl < 2; ++nl)
                    ck[md][nl] = mfma16(kfr[md][kk], ekf[nl][kk], ck[md][nl]);
        #pragma unroll
        for (int nl = 0; nl < 2; ++nl)
            kcf[nl] = xpose(ck[0][nl], ck[1][nl], 1.0f, lane);
        f32x4 cv[2][2];
        #pragma unroll
        for (int ml = 0; ml < 2; ++ml)
            #pragma unroll
            for (int nd = 0; nd < 2; ++nd) cv[ml][nd] = (f32x4){0, 0, 0, 0};
        #pragma unroll
        for (int kk = 0; kk < 2; ++kk)
            #pragma unroll
            for (int ml = 0; ml < 2; ++ml)
                #pragma unroll
                for (int nd = 0; nd < 2; ++nd)
                    cv[ml][nd] = mfma16(evf[ml][kk], vfr[nd][kk], cv[ml][nd]);
        #pragma unroll
        for (int nd = 0; nd < 2; ++nd)
            vcf[nd] = xpose(cv[0][nd], cv[1][nd], 1.0f, lane);
    }
    const short8 kbf = *(const short8*)(wsp + WS_KBF + (h * 64 + lane) * 8);
    short8 vbf[2];
    #pragma unroll
    for (int md = 0; md < 2; ++md)
        vbf[md] = *(const short8*)(wsp + WS_VBF + ((h * 2 + md) * 64 + lane) * 8);

    // ============ phase 2: scores/softmax/PV (wave-local) ============
    short* scr = (short*)smem + wave * 1024;   // 2KB/wave, 128 16B chunks
    // zero pad chunks (kk=1, lanes>=32), swizzled; never overwritten
    if (lane >= 32) {
        const int ch = (64 + lane) ^ ((lane >> 3) & 7);
        *(uint4*)(scr + ch * 8) = make_uint4(0, 0, 0, 0);
    }
    const int rdx0 = (lane ^ ((lane >> 3) & 7)) * 8;
    const int rdx1 = ((64 + lane) ^ ((lane >> 3) & 7)) * 8;

    #pragma unroll
    for (int th = 0; th < 2; ++th) {
        f32x4 sc[2][3];
        #pragma unroll
        for (int mt = 0; mt < 2; ++mt) {
            const short8 qa = qfr[th * 2 + mt];
            sc[mt][0] = mfma16(qa, kcf[0], (f32x4){0, 0, 0, 0});
            sc[mt][1] = mfma16(qa, kcf[1], (f32x4){0, 0, 0, 0});
            sc[mt][2] = mfma16(qa, kbf,    (f32x4){0, 0, 0, 0});
        }
        float inv[2][4];
        #pragma unroll
        for (int mt = 0; mt < 2; ++mt) {
            #pragma unroll
            for (int r = 0; r < 4; ++r) {
                float mm = fmaxf(fmaxf(sc[mt][0][r], sc[mt][1][r]), sc[mt][2][r]);
                mm = fmaxf(mm, __shfl_xor(mm, 1));
                mm = fmaxf(mm, __shfl_xor(mm, 2));
                mm = fmaxf(mm, __shfl_xor(mm, 4));
                mm = fmaxf(mm, __shfl_xor(mm, 8));
                const float e0 = __expf(sc[mt][0][r] - mm);
                const float e1 = __expf(sc[mt][1][r] - mm);
                const float e2 = __expf(sc[mt][2][r] - mm);
                sc[mt][0][r] = e0; sc[mt][1][r] = e1; sc[mt][2][r] = e2;
                float su = e0 + e1 + e2;
                su += __shfl_xor(su, 1);
                su += __shfl_xor(su, 2);
                su += __shfl_xor(su, 4);
                su += __shfl_xor(su, 8);
                inv[mt][r] = 1.0f / su;
            }
        }
        #pragma unroll
        for (int mt = 0; mt < 2; ++mt) {
            // scatter P (this mt) into swizzled frag chunks
            #pragma unroll
            for (int nk = 0; nk < 3; ++nk) {
                const int qt = (nk * 2 + (l16 >> 3)) & 3;
                const int kk = nk >> 1;
                const int xr = (qt * 2 + (quad >> 1)) & 7;
                #pragma unroll
                for (int r = 0; r < 4; ++r) {
                    const int ch = (kk * 64 + qt * 16 + quad * 4 + r) ^ xr;
                    scr[ch * 8 + (l16 & 7)] = (short)f2b(sc[mt][nk][r] * inv[mt][r]);
                }
            }
            asm volatile("s_waitcnt lgkmcnt(0)" ::: "memory");
            __builtin_amdgcn_sched_barrier(0);
            const short8 pa0 = *(const short8*)(scr + rdx0);
            const short8 pa1 = *(const short8*)(scr + rdx1);
            #pragma unroll
            for (int md = 0; md < 2; ++md) {
                f32x4 o = mfma16(vcf[md], pa0, (f32x4){0, 0, 0, 0});
                o = mfma16(vbf[md], pa1, o);
                *(uint2*)(attn + sw256((th * 2 + mt) * 16 + l16,
                                       h * 32 + md * 16 + quad * 4)) =
                    make_uint2(f2b2(o[0], o[1]), f2b2(o[2], o[3]));
            }
        }
    }
    __syncthreads();   // B5: attn ready

    // ============ phase 3: output projection ============
    {
        const short* Whp = wsp + WS_WHP;
        const short* Wlp = wsp + WS_WLP;
        f32x4 acc[2][4];
        #pragma unroll
        for (int p = 0; p < 2; ++p) {
            const float bi = bproj[(wave * 2 + p) * 16 + l16];
            #pragma unroll
            for (int m = 0; m < 4; ++m) acc[p][m] = (f32x4){bi, bi, bi, bi};
        }
        #pragma unroll 2
        for (int tk = 0; tk < 8; ++tk) {
            short8 aA[4];
            #pragma unroll
            for (int m = 0; m < 4; ++m)
                aA[m] = *(const short8*)(attn + sw256(m * 16 + l16, tk * 32 + quad * 8));
            #pragma unroll
            for (int p = 0; p < 2; ++p) {
                const int bo = (((wave * 2 + p) * 8 + tk) * 64 + lane) * 8;
                const short8 bh = *(const short8*)(Whp + bo);
                const short8 bl = *(const short8*)(Wlp + bo);
                #pragma unroll
                for (int m = 0; m < 4; ++m) {
                    acc[p][m] = mfma16(aA[m], bh, acc[p][m]);
                    acc[p][m] = mfma16(aA[m], bl, acc[p][m]);
                }
            }
        }
        #pragma unroll
        for (int p = 0; p < 2; ++p)
            #pragma unroll
            for (int m = 0; m < 4; ++m)
                #pragma unroll
                for (int r = 0; r < 4; ++r) {
                    const int t = m * 16 + quad * 4 + r;
                    const int n = (rw * 8 + (t >> 3)) * 64 + cw * 8 + (t & 7);
                    out[(size_t)(b * 4096 + n) * 256 + (wave * 2 + p) * 16 + l16] =
                        acc[p][m][r];
                }
    }
}

extern "C" void kernel_launch(void* const* d_in, const int* in_sizes, int n_in,
                              void* d_out, int out_size, void* d_ws, size_t ws_size,
                              hipStream_t stream) {
    const float* x     = (const float*)d_in[0];
    const float* Wqkv  = (const float*)d_in[1];
    const float* bqkv  = (const float*)d_in[2];
    const float* Ek    = (const float*)d_in[3];
    const float* Ev    = (const float*)d_in[4];
    const float* kbank = (const float*)d_in[5];
    const float* vbank = (const float*)d_in[6];
    const float* Wproj = (const float*)d_in[7];
    const float* bproj = (const float*)d_in[8];
    float* outp        = (float*)d_out;
    short* wsp         = (short*)d_ws;
    (void)in_sizes; (void)n_in; (void)out_size; (void)ws_size;

    (void)hipFuncSetAttribute((const void*)eswa_main,
                              hipFuncAttributeMaxDynamicSharedMemorySize, SMEM_BYTES);

    eswa_prep<<<259, 256, 0, stream>>>(Wqkv, Wproj, Ek, Ev, kbank, vbank, wsp);
    eswa_main<<<1024, 512, SMEM_BYTES, stream>>>(x, bqkv, bproj, wsp, outp);
}

// Round 6
// 186.258 us; speedup vs baseline: 3.5031x; 1.2210x over previous
//
#include <hip/hip_runtime.h>
#include <hip/hip_bf16.h>

// B=16, N=4096, C=256, WS=8 -> 1024 windows x 64 tokens; NH=8, HD=32, LK=32, G=16.
// R10: R7 structure (serial k/v/q GEMMs, (512,4) -> 64-VGPR point, wave-per-
//   head register dataflow) with LDS cut 64->48KB: full-x staging [64][256]
//   @0 (32KB) time-shares with phase-2 {P-scratch 16KB @0 + attn 32KB @16KB}
//   (xh dead after B2). P-bounce is R9's 2KB/wave XOR-swizzled conflict-free
//   scheme. 48KB x 3 = 144KB -> 3 blocks/CU if 64 regs/wave admits 6 waves/
//   SIMD; worst case 2 blocks (= R7, no regression).
// History: R8 (512,6) caused 40-VGPR cap -> 2GB spill; R9 no-bound -> 108
//   VGPR -> 1 block/CU, 145us. Occupancy is the lever: dur ~ 1/waves.

typedef unsigned int uint;
typedef __attribute__((ext_vector_type(8))) short short8;   // 8 x bf16
typedef __attribute__((ext_vector_type(4))) float f32x4;
typedef __attribute__((ext_vector_type(4))) uint uintx4;

__device__ __forceinline__ float bup(uint hs) {
    return __uint_as_float(hs << 16);
}
__device__ __forceinline__ uint f2b(float f) {   // fp32 -> bf16 bits (RNE, HW cvt)
    __hip_bfloat16 h = __float2bfloat16(f);
    unsigned short u;
    __builtin_memcpy(&u, &h, 2);
    return (uint)u;
}
__device__ __forceinline__ uint f2b2(float a, float b) {  // v_cvt_pk_bf16_f32
    __hip_bfloat162 h = __float22bfloat162_rn(make_float2(a, b));
    uint u;
    __builtin_memcpy(&u, &h, 4);
    return u;
}
__device__ __forceinline__ f32x4 mfma16(short8 a, short8 b, f32x4 c) {
    return __builtin_amdgcn_mfma_f32_16x16x32_bf16(a, b, c, 0, 0, 0);
}
__device__ __forceinline__ int sw256(int r, int c) { return r * 256 + (c ^ ((r & 7) << 3)); }

// C-layout pair (a = rows 0-15, b = rows 16-31; lane = col l16, per-reg rows
// quad*4+r) -> MFMA operand frag: lane (qf,l16) elem j = (row qf*8+j, col l16).
__device__ __forceinline__ short8 xpose(f32x4 a, f32x4 b, float s, int lane) {
    const uint pa0 = f2b2(a[0] * s, a[1] * s), pa1 = f2b2(a[2] * s, a[3] * s);
    const uint pb0 = f2b2(b[0] * s, b[1] * s), pb1 = f2b2(b[2] * s, b[3] * s);
    const int s0 = ((lane >> 4) & 1) * 32 + (lane & 15);
    const int s1 = s0 + 16;
    const uint w0a = __shfl(pa0, s0), w0b = __shfl(pb0, s0);
    const uint w1a = __shfl(pa1, s0), w1b = __shfl(pb1, s0);
    const uint w2a = __shfl(pa0, s1), w2b = __shfl(pb0, s1);
    const uint w3a = __shfl(pa1, s1), w3b = __shfl(pb1, s1);
    const bool hi = lane >= 32;
    uintx4 u;
    u[0] = hi ? w0b : w0a;
    u[1] = hi ? w1b : w1a;
    u[2] = hi ? w2b : w2a;
    u[3] = hi ? w3b : w3a;
    short8 r;
    __builtin_memcpy(&r, &u, 16);
    return r;
}

// ---- workspace layout (shorts) ----
#define WS_WHQ 0          // Wqkv frags [48 tn][8 tk][64 lane][8] = 196608
#define WS_WHP 196608     // Wproj hi [16 tn][8 tk][64][8] = 65536
#define WS_WLP 262144     // Wproj lo = 65536
#define WS_EKT 327680     // Ek frags [2 tm][2 tk][64][8] = 2048
#define WS_EVT 329728     // Ev frags = 2048
#define WS_KBF 331776     // kbank frags [8 h][64][8] = 4096
#define WS_VBF 335872     // vbank frags [8 h][2 md][64][8] = 8192 (quads>=2 zero)

__global__ void __launch_bounds__(256)
eswa_prep(const float* __restrict__ Wqkv, const float* __restrict__ Wproj,
          const float* __restrict__ Ek, const float* __restrict__ Ev,
          const float* __restrict__ kbank, const float* __restrict__ vbank,
          short* __restrict__ wsp)
{
    const int blk = blockIdx.x, thr = threadIdx.x;
    if (blk < 192) {                      // Wqkv frags
        const int jh = blk & 1;
        const int g = (blk >> 1) * 256 + thr;
        const int lane = g & 63, tk = (g >> 6) & 7, tn = g >> 9;
        const int quad = lane >> 4, l16 = lane & 15;
        const int c = tn * 16 + l16;
        const int r0 = tk * 32 + quad * 8 + jh * 4;
        const float w0 = Wqkv[(r0 + 0) * 768 + c], w1 = Wqkv[(r0 + 1) * 768 + c];
        const float w2 = Wqkv[(r0 + 2) * 768 + c], w3 = Wqkv[(r0 + 3) * 768 + c];
        *(uint2*)(wsp + WS_WHQ + ((tn * 8 + tk) * 64 + lane) * 8 + jh * 4) =
            make_uint2(f2b2(w0, w1), f2b2(w2, w3));
    } else if (blk < 256) {               // Wproj hi+lo
        const int idx = blk - 192, jh = idx & 1;
        const int g = (idx >> 1) * 256 + thr;
        const int lane = g & 63, tk = (g >> 6) & 7, tn = g >> 9;
        const int quad = lane >> 4, l16 = lane & 15;
        const int c = tn * 16 + l16;
        const int r0 = tk * 32 + quad * 8 + jh * 4;
        float w[4];
        #pragma unroll
        for (int j = 0; j < 4; ++j) w[j] = Wproj[(r0 + j) * 256 + c];
        const uint h01 = f2b2(w[0], w[1]), h23 = f2b2(w[2], w[3]);
        const float l0 = w[0] - bup(h01 & 0xffffu), l1 = w[1] - bup(h01 >> 16);
        const float l2 = w[2] - bup(h23 & 0xffffu), l3 = w[3] - bup(h23 >> 16);
        const int o = ((tn * 8 + tk) * 64 + lane) * 8 + jh * 4;
        *(uint2*)(wsp + WS_WHP + o) = make_uint2(h01, h23);
        *(uint2*)(wsp + WS_WLP + o) = make_uint2(f2b2(l0, l1), f2b2(l2, l3));
    } else if (blk < 258) {               // Ek (256) / Ev (257) frags
        const float* E = (blk == 256) ? Ek : Ev;
        const int base = (blk == 256) ? WS_EKT : WS_EVT;
        const int lane = thr & 63, tk = (thr >> 6) & 1, tm = (thr >> 7) & 1;
        const int quad = lane >> 4, l16 = lane & 15;
        const int lk = tm * 16 + l16;
        uint pk[4];
        #pragma unroll
        for (int jp = 0; jp < 4; ++jp) {
            const int t = tk * 32 + quad * 8 + jp * 2;
            pk[jp] = f2b2(E[t * 32 + lk], E[(t + 1) * 32 + lk]);
        }
        *(uint4*)(wsp + base + ((tm * 2 + tk) * 64 + lane) * 8) =
            make_uint4(pk[0], pk[1], pk[2], pk[3]);
    } else {                              // bank fragments
        for (int idx = thr; idx < 512; idx += 256) {
            const int hh = idx >> 6, l = idx & 63;
            const int l16 = l & 15, q = l >> 4;
            uint pk[4];
            #pragma unroll
            for (int jp = 0; jp < 4; ++jp)
                pk[jp] = f2b2(kbank[l16 * 256 + hh * 32 + q * 8 + jp * 2],
                              kbank[l16 * 256 + hh * 32 + q * 8 + jp * 2 + 1]);
            *(uint4*)(wsp + WS_KBF + idx * 8) = make_uint4(pk[0], pk[1], pk[2], pk[3]);
        }
        for (int idx = thr; idx < 1024; idx += 256) {
            const int hh = idx >> 7, md = (idx >> 6) & 1, l = idx & 63;
            const int l16 = l & 15, q = l >> 4;
            uint pk[4] = {0u, 0u, 0u, 0u};
            if (q < 2) {
                #pragma unroll
                for (int jp = 0; jp < 4; ++jp)
                    pk[jp] = f2b2(vbank[(q * 8 + jp * 2) * 256 + hh * 32 + md * 16 + l16],
                                  vbank[(q * 8 + jp * 2 + 1) * 256 + hh * 32 + md * 16 + l16]);
            }
            *(uint4*)(wsp + WS_VBF + idx * 8) = make_uint4(pk[0], pk[1], pk[2], pk[3]);
        }
    }
}

// ---- LDS (bytes), total 49152 (48KB -> up to 3 blocks/CU) ----
// phase 1: xh bf16 [64][256] sw256 @ 0        32768  (dead after B2)
// phase 2: P-scratch @ 0 (2KB/wave x 8)       16384
//          attn bf16 [64][256] sw256 @ 16384  32768
#define SMEM_BYTES 49152

__global__ void __launch_bounds__(512, 4)
eswa_main(const float* __restrict__ x, const float* __restrict__ bqkv,
          const float* __restrict__ bproj, const short* __restrict__ wsp,
          float* __restrict__ out)
{
    extern __shared__ char smem[];
    short* xh   = (short*)smem;            // [64][256] sw256 (phase 1)
    short* attn = (short*)smem + 8192;     // [64][256] sw256 (phase 2/3)

    const int tid  = threadIdx.x;
    const int wave = tid >> 6;             // 0..7 = head
    const int lane = tid & 63;
    const int quad = lane >> 4;
    const int l16  = lane & 15;
    const int h    = wave;

    const int b  = blockIdx.x >> 6;
    const int w  = blockIdx.x & 63;
    const int rw = w >> 3;
    const int cw = w & 7;

    // ================= stage: x -> bf16 LDS [token][256] swizzled ==========
    #pragma unroll
    for (int i = 0; i < 8; ++i) {
        const int vi = tid + 512 * i;             // 0..4095
        const int t  = vi >> 6;
        const int c  = (vi & 63) * 4;
        const int n  = (rw * 8 + (t >> 3)) * 64 + cw * 8 + (t & 7);
        const float4 xv = *(const float4*)(x + (size_t)(b * 4096 + n) * 256 + c);
        *(uint2*)(xh + sw256(t, c)) = make_uint2(f2b2(xv.x, xv.y), f2b2(xv.z, xv.w));
    }
    __syncthreads();   // B1

    const short* WF = wsp + WS_WHQ;

    // ================= phase 1 (per wave = head h) =================
    // ---- k GEMM: C[t][d] (lane=d), acc[nd][mt] -> kfr[nd][kk] = k^T frags
    short8 kfr[2][2], vfr[2][2];
    {
        f32x4 acc[2][4];
        #pragma unroll
        for (int nd = 0; nd < 2; ++nd) {
            const float bk = bqkv[256 + h * 32 + nd * 16 + l16];
            #pragma unroll
            for (int mt = 0; mt < 4; ++mt) acc[nd][mt] = (f32x4){bk, bk, bk, bk};
        }
        #pragma unroll 2
        for (int tk = 0; tk < 8; ++tk) {
            short8 xf[4];
            #pragma unroll
            for (int mt = 0; mt < 4; ++mt)
                xf[mt] = *(const short8*)(xh + sw256(mt * 16 + l16, tk * 32 + quad * 8));
            #pragma unroll
            for (int nd = 0; nd < 2; ++nd) {
                const short8 wf =
                    *(const short8*)(WF + (((16 + h * 2 + nd) * 8 + tk) * 64 + lane) * 8);
                #pragma unroll
                for (int mt = 0; mt < 4; ++mt) acc[nd][mt] = mfma16(xf[mt], wf, acc[nd][mt]);
            }
        }
        #pragma unroll
        for (int nd = 0; nd < 2; ++nd)
            #pragma unroll
            for (int kk = 0; kk < 2; ++kk)
                kfr[nd][kk] = xpose(acc[nd][2 * kk], acc[nd][2 * kk + 1], 1.0f, lane);
    }
    // ---- v GEMM (same structure)
    {
        f32x4 acc[2][4];
        #pragma unroll
        for (int nd = 0; nd < 2; ++nd) {
            const float bv = bqkv[512 + h * 32 + nd * 16 + l16];
            #pragma unroll
            for (int mt = 0; mt < 4; ++mt) acc[nd][mt] = (f32x4){bv, bv, bv, bv};
        }
        #pragma unroll 2
        for (int tk = 0; tk < 8; ++tk) {
            short8 xf[4];
            #pragma unroll
            for (int mt = 0; mt < 4; ++mt)
                xf[mt] = *(const short8*)(xh + sw256(mt * 16 + l16, tk * 32 + quad * 8));
            #pragma unroll
            for (int nd = 0; nd < 2; ++nd) {
                const short8 wf =
                    *(const short8*)(WF + (((32 + h * 2 + nd) * 8 + tk) * 64 + lane) * 8);
                #pragma unroll
                for (int mt = 0; mt < 4; ++mt) acc[nd][mt] = mfma16(xf[mt], wf, acc[nd][mt]);
            }
        }
        #pragma unroll
        for (int nd = 0; nd < 2; ++nd)
            #pragma unroll
            for (int kk = 0; kk < 2; ++kk)
                vfr[nd][kk] = xpose(acc[nd][2 * kk], acc[nd][2 * kk + 1], 1.0f, lane);
    }
    // ---- Linformer compression, all in registers
    short8 kcf[2], vcf[2];
    {
        short8 ekf[2][2], evf[2][2];
        #pragma unroll
        for (int tm = 0; tm < 2; ++tm)
            #pragma unroll
            for (int kk = 0; kk < 2; ++kk) {
                ekf[tm][kk] = *(const short8*)(wsp + WS_EKT + ((tm * 2 + kk) * 64 + lane) * 8);
                evf[tm][kk] = *(const short8*)(wsp + WS_EVT + ((tm * 2 + kk) * 64 + lane) * 8);
            }
        f32x4 ck[2][2];
        #pragma unroll
        for (int md = 0; md < 2; ++md)
            #pragma unroll
            for (int nl = 0; nl < 2; ++nl) ck[md][nl] = (f32x4){0, 0, 0, 0};
        #pragma unroll
        for (int kk = 0; kk < 2; ++kk)
            #pragma unroll
            for (int md = 0; md < 2; ++md)
                #pragma unroll
                for (int nl = 0; nl < 2; ++nl)
                    ck[md][nl] = mfma16(kfr[md][kk], ekf[nl][kk], ck[md][nl]);
        #pragma unroll
        for (int nl = 0; nl < 2; ++nl)
            kcf[nl] = xpose(ck[0][nl], ck[1][nl], 1.0f, lane);
        f32x4 cv[2][2];
        #pragma unroll
        for (int ml = 0; ml < 2; ++ml)
            #pragma unroll
            for (int nd = 0; nd < 2; ++nd) cv[ml][nd] = (f32x4){0, 0, 0, 0};
        #pragma unroll
        for (int kk = 0; kk < 2; ++kk)
            #pragma unroll
            for (int ml = 0; ml < 2; ++ml)
                #pragma unroll
                for (int nd = 0; nd < 2; ++nd)
                    cv[ml][nd] = mfma16(evf[ml][kk], vfr[nd][kk], cv[ml][nd]);
        #pragma unroll
        for (int nd = 0; nd < 2; ++nd)
            vcf[nd] = xpose(cv[0][nd], cv[1][nd], 1.0f, lane);
    }
    const short8 kbf = *(const short8*)(wsp + WS_KBF + (h * 64 + lane) * 8);
    short8 vbf[2];
    #pragma unroll
    for (int md = 0; md < 2; ++md)
        vbf[md] = *(const short8*)(wsp + WS_VBF + ((h * 2 + md) * 64 + lane) * 8);

    // ---- q GEMM transposed: C[d][t] (lane=t), acc[md][nt] -> qfr[nt] A-frags
    short8 qfr[4];
    {
        f32x4 acc[2][4];
        #pragma unroll
        for (int md = 0; md < 2; ++md) {
            const float4 bq = *(const float4*)(bqkv + h * 32 + md * 16 + quad * 4);
            #pragma unroll
            for (int nt = 0; nt < 4; ++nt) acc[md][nt] = (f32x4){bq.x, bq.y, bq.z, bq.w};
        }
        #pragma unroll 2
        for (int tk = 0; tk < 8; ++tk) {
            short8 xf[4];
            #pragma unroll
            for (int nt = 0; nt < 4; ++nt)
                xf[nt] = *(const short8*)(xh + sw256(nt * 16 + l16, tk * 32 + quad * 8));
            #pragma unroll
            for (int md = 0; md < 2; ++md) {
                const short8 wf =
                    *(const short8*)(WF + (((h * 2 + md) * 8 + tk) * 64 + lane) * 8);
                #pragma unroll
                for (int nt = 0; nt < 4; ++nt) acc[md][nt] = mfma16(wf, xf[nt], acc[md][nt]);
            }
        }
        #pragma unroll
        for (int nt = 0; nt < 4; ++nt)
            qfr[nt] = xpose(acc[0][nt], acc[1][nt], 0.17677669529663687f, lane);
    }
    __syncthreads();   // B2: xh dead -> P scratch @0, attn @16KB

    // ================= phase 2: scores/softmax/PV (wave-local) =============
    short* scr = (short*)smem + wave * 1024;   // 2KB/wave, 128 16B chunks
    // zero pad chunks (kk=1, lanes>=32), swizzled; never overwritten
    if (lane >= 32) {
        const int ch = (64 + lane) ^ ((lane >> 3) & 7);
        *(uint4*)(scr + ch * 8) = make_uint4(0, 0, 0, 0);
    }
    const int rdx0 = (lane ^ ((lane >> 3) & 7)) * 8;
    const int rdx1 = ((64 + lane) ^ ((lane >> 3) & 7)) * 8;

    #pragma unroll
    for (int th = 0; th < 2; ++th) {
        f32x4 sc[2][3];
        #pragma unroll
        for (int mt = 0; mt < 2; ++mt) {
            const short8 qa = qfr[th * 2 + mt];
            sc[mt][0] = mfma16(qa, kcf[0], (f32x4){0, 0, 0, 0});
            sc[mt][1] = mfma16(qa, kcf[1], (f32x4){0, 0, 0, 0});
            sc[mt][2] = mfma16(qa, kbf,    (f32x4){0, 0, 0, 0});
        }
        float inv[2][4];
        #pragma unroll
        for (int mt = 0; mt < 2; ++mt) {
            #pragma unroll
            for (int r = 0; r < 4; ++r) {
                float mm = fmaxf(fmaxf(sc[mt][0][r], sc[mt][1][r]), sc[mt][2][r]);
                mm = fmaxf(mm, __shfl_xor(mm, 1));
                mm = fmaxf(mm, __shfl_xor(mm, 2));
                mm = fmaxf(mm, __shfl_xor(mm, 4));
                mm = fmaxf(mm, __shfl_xor(mm, 8));
                const float e0 = __expf(sc[mt][0][r] - mm);
                const float e1 = __expf(sc[mt][1][r] - mm);
                const float e2 = __expf(sc[mt][2][r] - mm);
                sc[mt][0][r] = e0; sc[mt][1][r] = e1; sc[mt][2][r] = e2;
                float su = e0 + e1 + e2;
                su += __shfl_xor(su, 1);
                su += __shfl_xor(su, 2);
                su += __shfl_xor(su, 4);
                su += __shfl_xor(su, 8);
                inv[mt][r] = 1.0f / su;
            }
        }
        #pragma unroll
        for (int mt = 0; mt < 2; ++mt) {
            // scatter P (this mt) into swizzled frag chunks
            #pragma unroll
            for (int nk = 0; nk < 3; ++nk) {
                const int qt = (nk * 2 + (l16 >> 3)) & 3;
                const int kk = nk >> 1;
                const int xr = (qt * 2 + (quad >> 1)) & 7;
                #pragma unroll
                for (int r = 0; r < 4; ++r) {
                    const int ch = (kk * 64 + qt * 16 + quad * 4 + r) ^ xr;
                    scr[ch * 8 + (l16 & 7)] = (short)f2b(sc[mt][nk][r] * inv[mt][r]);
                }
            }
            asm volatile("s_waitcnt lgkmcnt(0)" ::: "memory");
            __builtin_amdgcn_sched_barrier(0);
            const short8 pa0 = *(const short8*)(scr + rdx0);
            const short8 pa1 = *(const short8*)(scr + rdx1);
            #pragma unroll
            for (int md = 0; md < 2; ++md) {
                f32x4 o = mfma16(vcf[md], pa0, (f32x4){0, 0, 0, 0});
                o = mfma16(vbf[md], pa1, o);
                *(uint2*)(attn + sw256((th * 2 + mt) * 16 + l16,
                                       h * 32 + md * 16 + quad * 4)) =
                    make_uint2(f2b2(o[0], o[1]), f2b2(o[2], o[3]));
            }
        }
    }
    __syncthreads();   // B3: attn ready

    // ================= phase 3: output projection =================
    {
        const short* Whp = wsp + WS_WHP;
        const short* Wlp = wsp + WS_WLP;
        f32x4 acc[2][4];
        #pragma unroll
        for (int p = 0; p < 2; ++p) {
            const float bi = bproj[(wave * 2 + p) * 16 + l16];
            #pragma unroll
            for (int m = 0; m < 4; ++m) acc[p][m] = (f32x4){bi, bi, bi, bi};
        }
        #pragma unroll 2
        for (int tk = 0; tk < 8; ++tk) {
            short8 aA[4];
            #pragma unroll
            for (int m = 0; m < 4; ++m)
                aA[m] = *(const short8*)(attn + sw256(m * 16 + l16, tk * 32 + quad * 8));
            #pragma unroll
            for (int p = 0; p < 2; ++p) {
                const int bo = (((wave * 2 + p) * 8 + tk) * 64 + lane) * 8;
                const short8 bh = *(const short8*)(Whp + bo);
                const short8 bl = *(const short8*)(Wlp + bo);
                #pragma unroll
                for (int m = 0; m < 4; ++m) {
                    acc[p][m] = mfma16(aA[m], bh, acc[p][m]);
                    acc[p][m] = mfma16(aA[m], bl, acc[p][m]);
                }
            }
        }
        #pragma unroll
        for (int p = 0; p < 2; ++p)
            #pragma unroll
            for (int m = 0; m < 4; ++m)
                #pragma unroll
                for (int r = 0; r < 4; ++r) {
                    const int t = m * 16 + quad * 4 + r;
                    const int n = (rw * 8 + (t >> 3)) * 64 + cw * 8 + (t & 7);
                    out[(size_t)(b * 4096 + n) * 256 + (wave * 2 + p) * 16 + l16] =
                        acc[p][m][r];
                }
    }
}

extern "C" void kernel_launch(void* const* d_in, const int* in_sizes, int n_in,
                              void* d_out, int out_size, void* d_ws, size_t ws_size,
                              hipStream_t stream) {
    const float* x     = (const float*)d_in[0];
    const float* Wqkv  = (const float*)d_in[1];
    const float* bqkv  = (const float*)d_in[2];
    const float* Ek    = (const float*)d_in[3];
    const float* Ev    = (const float*)d_in[4];
    const float* kbank = (const float*)d_in[5];
    const float* vbank = (const float*)d_in[6];
    const float* Wproj = (const float*)d_in[7];
    const float* bproj = (const float*)d_in[8];
    float* outp        = (float*)d_out;
    short* wsp         = (short*)d_ws;
    (void)in_sizes; (void)n_in; (void)out_size; (void)ws_size;

    (void)hipFuncSetAttribute((const void*)eswa_main,
                              hipFuncAttributeMaxDynamicSharedMemorySize, SMEM_BYTES);

    eswa_prep<<<259, 256, 0, stream>>>(Wqkv, Wproj, Ek, Ev, kbank, vbank, wsp);
    eswa_main<<<1024, 512, SMEM_BYTES, stream>>>(x, bqkv, bproj, wsp, outp);
}

// Round 8
// 176.557 us; speedup vs baseline: 3.6956x; 1.0549x over previous
//
#include <hip/hip_runtime.h>
#include <hip/hip_bf16.h>

// B=16, N=4096, C=256, WS=8 -> 1024 windows x 64 tokens; NH=8, HD=32, LK=32, G=16.
// R11: transposed QK^T (S^T = mfma(kcf, qfr) -- same frags, swapped roles)
//   puts P^T key-major in C-layout -> xpose transposes it in-register to the
//   PV B-operand. LDS P-bounce deleted; softmax reduce is cross-quad
//   (2 shfls); 1/sum applied as xpose's per-lane scale. LDS 48->32KB
//   (attn overlays dead xh @0) -> 4 blocks/CU at the 64-VGPR (512,4) point
//   -> whole 1024-block grid co-resident, no tail.
// History: R10 84us @3 blocks; R9 108 VGPR -> 1 block 145us; R8 (512,6)
//   40-VGPR cap -> spill. Rules: cap=256/min_waves; dur ~ 1/resident-waves.
// (R11 resubmit: previous round was an infra failure, not a kernel error.)

typedef unsigned int uint;
typedef __attribute__((ext_vector_type(8))) short short8;   // 8 x bf16
typedef __attribute__((ext_vector_type(4))) float f32x4;
typedef __attribute__((ext_vector_type(4))) uint uintx4;

__device__ __forceinline__ float bup(uint hs) {
    return __uint_as_float(hs << 16);
}
__device__ __forceinline__ uint f2b(float f) {   // fp32 -> bf16 bits (RNE, HW cvt)
    __hip_bfloat16 h = __float2bfloat16(f);
    unsigned short u;
    __builtin_memcpy(&u, &h, 2);
    return (uint)u;
}
__device__ __forceinline__ uint f2b2(float a, float b) {  // v_cvt_pk_bf16_f32
    __hip_bfloat162 h = __float22bfloat162_rn(make_float2(a, b));
    uint u;
    __builtin_memcpy(&u, &h, 4);
    return u;
}
__device__ __forceinline__ f32x4 mfma16(short8 a, short8 b, f32x4 c) {
    return __builtin_amdgcn_mfma_f32_16x16x32_bf16(a, b, c, 0, 0, 0);
}
__device__ __forceinline__ int sw256(int r, int c) { return r * 256 + (c ^ ((r & 7) << 3)); }

// C-layout pair (a = rows 0-15, b = rows 16-31; lane = col l16, per-reg rows
// quad*4+r) -> MFMA operand frag: lane (qf,l16) elem j = (row qf*8+j, col l16).
// s is a per-lane scale; source lane's l16 == dest lane's l16, so a per-column
// (per-token) scale is applied correctly.
__device__ __forceinline__ short8 xpose(f32x4 a, f32x4 b, float s, int lane) {
    const uint pa0 = f2b2(a[0] * s, a[1] * s), pa1 = f2b2(a[2] * s, a[3] * s);
    const uint pb0 = f2b2(b[0] * s, b[1] * s), pb1 = f2b2(b[2] * s, b[3] * s);
    const int s0 = ((lane >> 4) & 1) * 32 + (lane & 15);
    const int s1 = s0 + 16;
    const uint w0a = __shfl(pa0, s0), w0b = __shfl(pb0, s0);
    const uint w1a = __shfl(pa1, s0), w1b = __shfl(pb1, s0);
    const uint w2a = __shfl(pa0, s1), w2b = __shfl(pb0, s1);
    const uint w3a = __shfl(pa1, s1), w3b = __shfl(pb1, s1);
    const bool hi = lane >= 32;
    uintx4 u;
    u[0] = hi ? w0b : w0a;
    u[1] = hi ? w1b : w1a;
    u[2] = hi ? w2b : w2a;
    u[3] = hi ? w3b : w3a;
    short8 r;
    __builtin_memcpy(&r, &u, 16);
    return r;
}

// ---- workspace layout (shorts) ----
#define WS_WHQ 0          // Wqkv frags [48 tn][8 tk][64 lane][8] = 196608
#define WS_WHP 196608     // Wproj hi [16 tn][8 tk][64][8] = 65536
#define WS_WLP 262144     // Wproj lo = 65536
#define WS_EKT 327680     // Ek frags [2 tm][2 tk][64][8] = 2048
#define WS_EVT 329728     // Ev frags = 2048
#define WS_KBF 331776     // kbank frags [8 h][64][8] = 4096
#define WS_VBF 335872     // vbank frags [8 h][2 md][64][8] = 8192 (quads>=2 zero)

__global__ void __launch_bounds__(256)
eswa_prep(const float* __restrict__ Wqkv, const float* __restrict__ Wproj,
          const float* __restrict__ Ek, const float* __restrict__ Ev,
          const float* __restrict__ kbank, const float* __restrict__ vbank,
          short* __restrict__ wsp)
{
    const int blk = blockIdx.x, thr = threadIdx.x;
    if (blk < 192) {                      // Wqkv frags
        const int jh = blk & 1;
        const int g = (blk >> 1) * 256 + thr;
        const int lane = g & 63, tk = (g >> 6) & 7, tn = g >> 9;
        const int quad = lane >> 4, l16 = lane & 15;
        const int c = tn * 16 + l16;
        const int r0 = tk * 32 + quad * 8 + jh * 4;
        const float w0 = Wqkv[(r0 + 0) * 768 + c], w1 = Wqkv[(r0 + 1) * 768 + c];
        const float w2 = Wqkv[(r0 + 2) * 768 + c], w3 = Wqkv[(r0 + 3) * 768 + c];
        *(uint2*)(wsp + WS_WHQ + ((tn * 8 + tk) * 64 + lane) * 8 + jh * 4) =
            make_uint2(f2b2(w0, w1), f2b2(w2, w3));
    } else if (blk < 256) {               // Wproj hi+lo
        const int idx = blk - 192, jh = idx & 1;
        const int g = (idx >> 1) * 256 + thr;
        const int lane = g & 63, tk = (g >> 6) & 7, tn = g >> 9;
        const int quad = lane >> 4, l16 = lane & 15;
        const int c = tn * 16 + l16;
        const int r0 = tk * 32 + quad * 8 + jh * 4;
        float w[4];
        #pragma unroll
        for (int j = 0; j < 4; ++j) w[j] = Wproj[(r0 + j) * 256 + c];
        const uint h01 = f2b2(w[0], w[1]), h23 = f2b2(w[2], w[3]);
        const float l0 = w[0] - bup(h01 & 0xffffu), l1 = w[1] - bup(h01 >> 16);
        const float l2 = w[2] - bup(h23 & 0xffffu), l3 = w[3] - bup(h23 >> 16);
        const int o = ((tn * 8 + tk) * 64 + lane) * 8 + jh * 4;
        *(uint2*)(wsp + WS_WHP + o) = make_uint2(h01, h23);
        *(uint2*)(wsp + WS_WLP + o) = make_uint2(f2b2(l0, l1), f2b2(l2, l3));
    } else if (blk < 258) {               // Ek (256) / Ev (257) frags
        const float* E = (blk == 256) ? Ek : Ev;
        const int base = (blk == 256) ? WS_EKT : WS_EVT;
        const int lane = thr & 63, tk = (thr >> 6) & 1, tm = (thr >> 7) & 1;
        const int quad = lane >> 4, l16 = lane & 15;
        const int lk = tm * 16 + l16;
        uint pk[4];
        #pragma unroll
        for (int jp = 0; jp < 4; ++jp) {
            const int t = tk * 32 + quad * 8 + jp * 2;
            pk[jp] = f2b2(E[t * 32 + lk], E[(t + 1) * 32 + lk]);
        }
        *(uint4*)(wsp + base + ((tm * 2 + tk) * 64 + lane) * 8) =
            make_uint4(pk[0], pk[1], pk[2], pk[3]);
    } else {                              // bank fragments
        for (int idx = thr; idx < 512; idx += 256) {
            const int hh = idx >> 6, l = idx & 63;
            const int l16 = l & 15, q = l >> 4;
            uint pk[4];
            #pragma unroll
            for (int jp = 0; jp < 4; ++jp)
                pk[jp] = f2b2(kbank[l16 * 256 + hh * 32 + q * 8 + jp * 2],
                              kbank[l16 * 256 + hh * 32 + q * 8 + jp * 2 + 1]);
            *(uint4*)(wsp + WS_KBF + idx * 8) = make_uint4(pk[0], pk[1], pk[2], pk[3]);
        }
        for (int idx = thr; idx < 1024; idx += 256) {
            const int hh = idx >> 7, md = (idx >> 6) & 1, l = idx & 63;
            const int l16 = l & 15, q = l >> 4;
            uint pk[4] = {0u, 0u, 0u, 0u};
            if (q < 2) {
                #pragma unroll
                for (int jp = 0; jp < 4; ++jp)
                    pk[jp] = f2b2(vbank[(q * 8 + jp * 2) * 256 + hh * 32 + md * 16 + l16],
                                  vbank[(q * 8 + jp * 2 + 1) * 256 + hh * 32 + md * 16 + l16]);
            }
            *(uint4*)(wsp + WS_VBF + idx * 8) = make_uint4(pk[0], pk[1], pk[2], pk[3]);
        }
    }
}

// ---- LDS (bytes), total 32768 (32KB -> 4 blocks/CU at 64 VGPR) ----
// phase 1:   xh   bf16 [64][256] sw256 @ 0   32768  (dead after B2)
// phase 2/3: attn bf16 [64][256] sw256 @ 0   32768  (overlays xh)
#define SMEM_BYTES 32768

__global__ void __launch_bounds__(512, 4)
eswa_main(const float* __restrict__ x, const float* __restrict__ bqkv,
          const float* __restrict__ bproj, const short* __restrict__ wsp,
          float* __restrict__ out)
{
    extern __shared__ char smem[];
    short* xh   = (short*)smem;            // [64][256] sw256 (phase 1)
    short* attn = (short*)smem;            // [64][256] sw256 (phase 2/3, after B2)

    const int tid  = threadIdx.x;
    const int wave = tid >> 6;             // 0..7 = head
    const int lane = tid & 63;
    const int quad = lane >> 4;
    const int l16  = lane & 15;
    const int h    = wave;

    const int b  = blockIdx.x >> 6;
    const int w  = blockIdx.x & 63;
    const int rw = w >> 3;
    const int cw = w & 7;

    // ================= stage: x -> bf16 LDS [token][256] swizzled ==========
    #pragma unroll
    for (int i = 0; i < 8; ++i) {
        const int vi = tid + 512 * i;             // 0..4095
        const int t  = vi >> 6;
        const int c  = (vi & 63) * 4;
        const int n  = (rw * 8 + (t >> 3)) * 64 + cw * 8 + (t & 7);
        const float4 xv = *(const float4*)(x + (size_t)(b * 4096 + n) * 256 + c);
        *(uint2*)(xh + sw256(t, c)) = make_uint2(f2b2(xv.x, xv.y), f2b2(xv.z, xv.w));
    }
    __syncthreads();   // B1

    const short* WF = wsp + WS_WHQ;

    // ================= phase 1 (per wave = head h) =================
    // ---- k GEMM: C[t][d] (lane=d), acc[nd][mt] -> kfr[nd][kk] = k^T frags
    short8 kfr[2][2], vfr[2][2];
    {
        f32x4 acc[2][4];
        #pragma unroll
        for (int nd = 0; nd < 2; ++nd) {
            const float bk = bqkv[256 + h * 32 + nd * 16 + l16];
            #pragma unroll
            for (int mt = 0; mt < 4; ++mt) acc[nd][mt] = (f32x4){bk, bk, bk, bk};
        }
        #pragma unroll 2
        for (int tk = 0; tk < 8; ++tk) {
            short8 xf[4];
            #pragma unroll
            for (int mt = 0; mt < 4; ++mt)
                xf[mt] = *(const short8*)(xh + sw256(mt * 16 + l16, tk * 32 + quad * 8));
            #pragma unroll
            for (int nd = 0; nd < 2; ++nd) {
                const short8 wf =
                    *(const short8*)(WF + (((16 + h * 2 + nd) * 8 + tk) * 64 + lane) * 8);
                #pragma unroll
                for (int mt = 0; mt < 4; ++mt) acc[nd][mt] = mfma16(xf[mt], wf, acc[nd][mt]);
            }
        }
        #pragma unroll
        for (int nd = 0; nd < 2; ++nd)
            #pragma unroll
            for (int kk = 0; kk < 2; ++kk)
                kfr[nd][kk] = xpose(acc[nd][2 * kk], acc[nd][2 * kk + 1], 1.0f, lane);
    }
    // ---- v GEMM (same structure)
    {
        f32x4 acc[2][4];
        #pragma unroll
        for (int nd = 0; nd < 2; ++nd) {
            const float bv = bqkv[512 + h * 32 + nd * 16 + l16];
            #pragma unroll
            for (int mt = 0; mt < 4; ++mt) acc[nd][mt] = (f32x4){bv, bv, bv, bv};
        }
        #pragma unroll 2
        for (int tk = 0; tk < 8; ++tk) {
            short8 xf[4];
            #pragma unroll
            for (int mt = 0; mt < 4; ++mt)
                xf[mt] = *(const short8*)(xh + sw256(mt * 16 + l16, tk * 32 + quad * 8));
            #pragma unroll
            for (int nd = 0; nd < 2; ++nd) {
                const short8 wf =
                    *(const short8*)(WF + (((32 + h * 2 + nd) * 8 + tk) * 64 + lane) * 8);
                #pragma unroll
                for (int mt = 0; mt < 4; ++mt) acc[nd][mt] = mfma16(xf[mt], wf, acc[nd][mt]);
            }
        }
        #pragma unroll
        for (int nd = 0; nd < 2; ++nd)
            #pragma unroll
            for (int kk = 0; kk < 2; ++kk)
                vfr[nd][kk] = xpose(acc[nd][2 * kk], acc[nd][2 * kk + 1], 1.0f, lane);
    }
    // ---- Linformer compression, all in registers
    short8 kcf[2], vcf[2];
    {
        short8 ekf[2][2], evf[2][2];
        #pragma unroll
        for (int tm = 0; tm < 2; ++tm)
            #pragma unroll
            for (int kk = 0; kk < 2; ++kk) {
                ekf[tm][kk] = *(const short8*)(wsp + WS_EKT + ((tm * 2 + kk) * 64 + lane) * 8);
                evf[tm][kk] = *(const short8*)(wsp + WS_EVT + ((tm * 2 + kk) * 64 + lane) * 8);
            }
        f32x4 ck[2][2];
        #pragma unroll
        for (int md = 0; md < 2; ++md)
            #pragma unroll
            for (int nl = 0; nl < 2; ++nl) ck[md][nl] = (f32x4){0, 0, 0, 0};
        #pragma unroll
        for (int kk = 0; kk < 2; ++kk)
            #pragma unroll
            for (int md = 0; md < 2; ++md)
                #pragma unroll
                for (int nl = 0; nl < 2; ++nl)
                    ck[md][nl] = mfma16(kfr[md][kk], ekf[nl][kk], ck[md][nl]);
        #pragma unroll
        for (int nl = 0; nl < 2; ++nl)
            kcf[nl] = xpose(ck[0][nl], ck[1][nl], 1.0f, lane);
        f32x4 cv[2][2];
        #pragma unroll
        for (int ml = 0; ml < 2; ++ml)
            #pragma unroll
            for (int nd = 0; nd < 2; ++nd) cv[ml][nd] = (f32x4){0, 0, 0, 0};
        #pragma unroll
        for (int kk = 0; kk < 2; ++kk)
            #pragma unroll
            for (int ml = 0; ml < 2; ++ml)
                #pragma unroll
                for (int nd = 0; nd < 2; ++nd)
                    cv[ml][nd] = mfma16(evf[ml][kk], vfr[nd][kk], cv[ml][nd]);
        #pragma unroll
        for (int nd = 0; nd < 2; ++nd)
            vcf[nd] = xpose(cv[0][nd], cv[1][nd], 1.0f, lane);
    }
    const short8 kbf = *(const short8*)(wsp + WS_KBF + (h * 64 + lane) * 8);
    short8 vbf[2];
    #pragma unroll
    for (int md = 0; md < 2; ++md)
        vbf[md] = *(const short8*)(wsp + WS_VBF + ((h * 2 + md) * 64 + lane) * 8);

    // ---- q GEMM transposed: C[d][t] (lane=t), acc[md][nt] -> qfr[nt] frags
    short8 qfr[4];
    {
        f32x4 acc[2][4];
        #pragma unroll
        for (int md = 0; md < 2; ++md) {
            const float4 bq = *(const float4*)(bqkv + h * 32 + md * 16 + quad * 4);
            #pragma unroll
            for (int nt = 0; nt < 4; ++nt) acc[md][nt] = (f32x4){bq.x, bq.y, bq.z, bq.w};
        }
        #pragma unroll 2
        for (int tk = 0; tk < 8; ++tk) {
            short8 xf[4];
            #pragma unroll
            for (int nt = 0; nt < 4; ++nt)
                xf[nt] = *(const short8*)(xh + sw256(nt * 16 + l16, tk * 32 + quad * 8));
            #pragma unroll
            for (int md = 0; md < 2; ++md) {
                const short8 wf =
                    *(const short8*)(WF + (((h * 2 + md) * 8 + tk) * 64 + lane) * 8);
                #pragma unroll
                for (int nt = 0; nt < 4; ++nt) acc[md][nt] = mfma16(wf, xf[nt], acc[md][nt]);
            }
        }
        #pragma unroll
        for (int nt = 0; nt < 4; ++nt)
            qfr[nt] = xpose(acc[0][nt], acc[1][nt], 0.17677669529663687f, lane);
    }
    __syncthreads();   // B2: xh dead -> attn overlays it

    // ====== phase 2: transposed scores / softmax / PV, all in registers =====
    // S^T[key][t] = mfma(kcf/kbf as A, qfr as B): lane = t, rows = keys.
    const f32x4 zero4 = (f32x4){0, 0, 0, 0};
    #pragma unroll
    for (int tt = 0; tt < 4; ++tt) {
        f32x4 sc[3];
        sc[0] = mfma16(kcf[0], qfr[tt], zero4);
        sc[1] = mfma16(kcf[1], qfr[tt], zero4);
        sc[2] = mfma16(kbf,    qfr[tt], zero4);
        // softmax over 48 keys: 12 in-lane values + cross-quad reduce
        float mm = sc[0][0];
        #pragma unroll
        for (int n = 0; n < 3; ++n)
            #pragma unroll
            for (int r = 0; r < 4; ++r) mm = fmaxf(mm, sc[n][r]);
        mm = fmaxf(mm, __shfl_xor(mm, 16));
        mm = fmaxf(mm, __shfl_xor(mm, 32));
        float su = 0.0f;
        #pragma unroll
        for (int n = 0; n < 3; ++n)
            #pragma unroll
            for (int r = 0; r < 4; ++r) {
                const float e = __expf(sc[n][r] - mm);
                sc[n][r] = e;
                su += e;
            }
        su += __shfl_xor(su, 16);
        su += __shfl_xor(su, 32);
        const float inv = 1.0f / su;
        // P^T -> PV B-operand frags via in-register transpose, scaled by 1/sum
        const short8 pa0 = xpose(sc[0], sc[1], inv, lane);   // keys 0..31
        const short8 pa1 = xpose(sc[2], zero4, inv, lane);   // keys 32..47 (+pad)
        #pragma unroll
        for (int md = 0; md < 2; ++md) {
            f32x4 o = mfma16(vcf[md], pa0, zero4);
            o = mfma16(vbf[md], pa1, o);
            *(uint2*)(attn + sw256(tt * 16 + l16, h * 32 + md * 16 + quad * 4)) =
                make_uint2(f2b2(o[0], o[1]), f2b2(o[2], o[3]));
        }
    }
    __syncthreads();   // B3: attn ready

    // ================= phase 3: output projection =================
    {
        const short* Whp = wsp + WS_WHP;
        const short* Wlp = wsp + WS_WLP;
        f32x4 acc[2][4];
        #pragma unroll
        for (int p = 0; p < 2; ++p) {
            const float bi = bproj[(wave * 2 + p) * 16 + l16];
            #pragma unroll
            for (int m = 0; m < 4; ++m) acc[p][m] = (f32x4){bi, bi, bi, bi};
        }
        #pragma unroll 2
        for (int tk = 0; tk < 8; ++tk) {
            short8 aA[4];
            #pragma unroll
            for (int m = 0; m < 4; ++m)
                aA[m] = *(const short8*)(attn + sw256(m * 16 + l16, tk * 32 + quad * 8));
            #pragma unroll
            for (int p = 0; p < 2; ++p) {
                const int bo = (((wave * 2 + p) * 8 + tk) * 64 + lane) * 8;
                const short8 bh = *(const short8*)(Whp + bo);
                const short8 bl = *(const short8*)(Wlp + bo);
                #pragma unroll
                for (int m = 0; m < 4; ++m) {
                    acc[p][m] = mfma16(aA[m], bh, acc[p][m]);
                    acc[p][m] = mfma16(aA[m], bl, acc[p][m]);
                }
            }
        }
        #pragma unroll
        for (int p = 0; p < 2; ++p)
            #pragma unroll
            for (int m = 0; m < 4; ++m)
                #pragma unroll
                for (int r = 0; r < 4; ++r) {
                    const int t = m * 16 + quad * 4 + r;
                    const int n = (rw * 8 + (t >> 3)) * 64 + cw * 8 + (t & 7);
                    out[(size_t)(b * 4096 + n) * 256 + (wave * 2 + p) * 16 + l16] =
                        acc[p][m][r];
                }
    }
}

extern "C" void kernel_launch(void* const* d_in, const int* in_sizes, int n_in,
                              void* d_out, int out_size, void* d_ws, size_t ws_size,
                              hipStream_t stream) {
    const float* x     = (const float*)d_in[0];
    const float* Wqkv  = (const float*)d_in[1];
    const float* bqkv  = (const float*)d_in[2];
    const float* Ek    = (const float*)d_in[3];
    const float* Ev    = (const float*)d_in[4];
    const float* kbank = (const float*)d_in[5];
    const float* vbank = (const float*)d_in[6];
    const float* Wproj = (const float*)d_in[7];
    const float* bproj = (const float*)d_in[8];
    float* outp        = (float*)d_out;
    short* wsp         = (short*)d_ws;
    (void)in_sizes; (void)n_in; (void)out_size; (void)ws_size;

    (void)hipFuncSetAttribute((const void*)eswa_main,
                              hipFuncAttributeMaxDynamicSharedMemorySize, SMEM_BYTES);

    eswa_prep<<<259, 256, 0, stream>>>(Wqkv, Wproj, Ek, Ev, kbank, vbank, wsp);
    eswa_main<<<1024, 512, SMEM_BYTES, stream>>>(x, bqkv, bproj, wsp, outp);
}